// Round 1
// baseline (159.359 us; speedup 1.0000x reference)
//
#include <hip/hip_runtime.h>

// Problem constants (B=4, S=2048, H=1024, E=8)
#define H 1024
#define E 8
#define T 8192          // B*S
#define CAP 1024        // T/E, capacity_factor=1.0 top-1

typedef __bf16 bf16x8 __attribute__((ext_vector_type(8)));
typedef float  f32x4  __attribute__((ext_vector_type(4)));
typedef unsigned short u16;

// round-to-nearest-even f32 -> bf16 bits
__device__ __forceinline__ u16 f2bf(float f) {
    union { float f; unsigned u; } v; v.f = f;
    unsigned r = v.u + 0x7FFFu + ((v.u >> 16) & 1u);
    return (u16)(r >> 16);
}

// packed f32x2 -> bf16x2 (RNE), gfx950 hw instruction (no builtin)
__device__ __forceinline__ unsigned cvt2bf(float lo, float hi) {
    unsigned r;
    asm("v_cvt_pk_bf16_f32 %0, %1, %2" : "=v"(r) : "v"(lo), "v"(hi));
    return r;
}

// async global->LDS, 16 B per lane
typedef __attribute__((address_space(1))) const void* gas_t;
typedef __attribute__((address_space(3))) void* las_t;
__device__ __forceinline__ void gld16(const void* g, void* l) {
    __builtin_amdgcn_global_load_lds((gas_t)g, (las_t)l, 16, 0, 0);
}

// ---------------------------------------------------------------------------
// Kernel 1: gating + x->bf16. wg transposed into LDS per block (kills the
// separate wgt kernel). 512 blocks x 16 tokens (4/wave). No W conversion:
// the GEMM now eats W fp32 directly.
// ---------------------------------------------------------------------------
__global__ __launch_bounds__(256) void gate_kernel(
    const float* __restrict__ x, const float* __restrict__ wg,
    int* __restrict__ eid, float* __restrict__ gate, u16* __restrict__ xbf) {
    __shared__ float wgs[E][H];     // 32 KB
    const int tid = threadIdx.x;

    {   // transpose wg [H][E] -> wgs [E][H]; 4 rows/thread
        const int h0 = tid * 4;
        float4 lo[4], hi[4];
        #pragma unroll
        for (int r = 0; r < 4; ++r) {
            const float4* p = (const float4*)(wg + (size_t)(h0 + r) * E);
            lo[r] = p[0]; hi[r] = p[1];
        }
        #pragma unroll
        for (int e = 0; e < 4; ++e) {
            float4 v0 = make_float4(((const float*)&lo[0])[e], ((const float*)&lo[1])[e],
                                    ((const float*)&lo[2])[e], ((const float*)&lo[3])[e]);
            *(float4*)&wgs[e][h0] = v0;
            float4 v1 = make_float4(((const float*)&hi[0])[e], ((const float*)&hi[1])[e],
                                    ((const float*)&hi[2])[e], ((const float*)&hi[3])[e]);
            *(float4*)&wgs[e + 4][h0] = v1;
        }
    }
    __syncthreads();

    const int wv = tid >> 6, lane = tid & 63;
    const int tbase = blockIdx.x * 16 + wv * 4;
    const int h00 = lane * 4;

    float a[4][8];
    #pragma unroll
    for (int j = 0; j < 4; ++j)
        #pragma unroll
        for (int e = 0; e < 8; ++e) a[j][e] = 0.f;

    #pragma unroll
    for (int q = 0; q < 4; ++q) {
        const int h0 = q * 256 + h00;
        float4 xv[4];
        #pragma unroll
        for (int j = 0; j < 4; ++j)
            xv[j] = *(const float4*)(x + (size_t)(tbase + j) * H + h0);
        #pragma unroll
        for (int j = 0; j < 4; ++j) {
            ushort4 o;
            o.x = f2bf(xv[j].x); o.y = f2bf(xv[j].y);
            o.z = f2bf(xv[j].z); o.w = f2bf(xv[j].w);
            *(ushort4*)(xbf + (size_t)(tbase + j) * H + h0) = o;
        }
        #pragma unroll
        for (int e = 0; e < 8; ++e) {
            const float4 w4 = *(const float4*)&wgs[e][h0];
            #pragma unroll
            for (int j = 0; j < 4; ++j)
                a[j][e] += xv[j].x * w4.x + xv[j].y * w4.y
                         + xv[j].z * w4.z + xv[j].w * w4.w;
        }
    }

    const bool b0 = lane & 1, b1 = lane & 2, b2 = lane & 4;
    const int elane = ((lane & 1) << 2) | (lane & 2) | ((lane >> 2) & 1);

    #pragma unroll
    for (int j = 0; j < 4; ++j) {
        float* A = a[j];
        #pragma unroll
        for (int k = 0; k < 4; ++k) {
            float t = b0 ? A[k] : A[k + 4];
            t = __shfl_xor(t, 1);
            A[k] = (b0 ? A[k + 4] : A[k]) + t;
        }
        #pragma unroll
        for (int k = 0; k < 2; ++k) {
            float t = b1 ? A[k] : A[k + 2];
            t = __shfl_xor(t, 2);
            A[k] = (b1 ? A[k + 2] : A[k]) + t;
        }
        {
            float t = b2 ? A[0] : A[1];
            t = __shfl_xor(t, 4);
            A[0] = (b2 ? A[1] : A[0]) + t;
        }
        float v = A[0];
        v += __shfl_xor(v, 8); v += __shfl_xor(v, 16); v += __shfl_xor(v, 32);
        float m = v; int mi = elane;
        #pragma unroll
        for (int off = 1; off <= 4; off <<= 1) {
            float om = __shfl_xor(m, off);
            int   oi = __shfl_xor(mi, off);
            if (om > m || (om == m && oi < mi)) { m = om; mi = oi; }
        }
        float s = expf(v - m);
        s += __shfl_xor(s, 1); s += __shfl_xor(s, 2); s += __shfl_xor(s, 4);
        if (lane == 0) {
            eid[tbase + j]  = mi;
            gate[tbase + j] = 1.0f / s;
        }
    }
}

// ---------------------------------------------------------------------------
// Kernel 2: capacity scan, 1024 threads (was 256): serial depth 32 -> 8.
// ---------------------------------------------------------------------------
#define SCAN_T 1024
#define STPT 8
__global__ __launch_bounds__(1024) void scan_kernel(
    const int* __restrict__ eid, float* __restrict__ gate,
    int* __restrict__ perm) {
    __shared__ int cnt[SCAN_T][E];     // 32 KB
    __shared__ int part[E][32];
    const int tid = threadIdx.x;

    for (int i = tid; i < E * CAP; i += SCAN_T) perm[i] = -1;

    const int t0 = tid * STPT;
    int ei[STPT];
    #pragma unroll
    for (int i = 0; i < STPT; ++i) ei[i] = eid[t0 + i];

    int c[E];
    #pragma unroll
    for (int e = 0; e < E; ++e) c[e] = 0;
    #pragma unroll
    for (int i = 0; i < STPT; ++i)
        #pragma unroll
        for (int e = 0; e < E; ++e) c[e] += (ei[i] == e);
    #pragma unroll
    for (int e = 0; e < E; ++e) cnt[tid][e] = c[e];
    __syncthreads();

    if (tid < 256) {                       // 8 experts x 32 groups of 32
        const int e = tid >> 5, g = tid & 31;
        int s = 0;
        for (int i = g * 32; i < g * 32 + 32; ++i) s += cnt[i][e];
        part[e][g] = s;
    }
    __syncthreads();
    if (tid < E) {
        int run = 0;
        #pragma unroll
        for (int g = 0; g < 32; ++g) { int v = part[tid][g]; part[tid][g] = run; run += v; }
    }
    __syncthreads();
    if (tid < 256) {                       // scatter exclusive bases back into cnt
        const int e = tid >> 5, g = tid & 31;
        int run = part[e][g];
        for (int i = g * 32; i < g * 32 + 32; ++i) { int v = cnt[i][e]; cnt[i][e] = run; run += v; }
    }
    __syncthreads();

    #pragma unroll
    for (int e = 0; e < E; ++e) c[e] = cnt[tid][e];
    #pragma unroll
    for (int i = 0; i < STPT; ++i) {
        const int t = t0 + i, e0 = ei[i];
        int pos = 0;
        #pragma unroll
        for (int k = 0; k < E; ++k) if (e0 == k) pos = c[k]++;
        if (pos < CAP) perm[e0 * CAP + pos] = t;
        else gate[t] = 0.f;               // dropped; kept tokens have gate >= 1/8
    }
}

// ---------------------------------------------------------------------------
// Kernel 3: gathered GEMM. A: bf16 via global_load_lds (as before).
// B: reg-staged fp32 W -> v_cvt_pk_bf16_f32 -> swizzled ds_write_b128;
// next-kt B loads prefetched during the compute phase (packed pw = 16 VGPR),
// so the pre-barrier vmcnt(0) drain finds them already complete.
// Blocks [0,64): zero-dropped-rows plane (first, to avoid a tail).
// ---------------------------------------------------------------------------
__global__ __launch_bounds__(512, 4) void moe_gemm_bf(
    const u16* __restrict__ xbf, const float* __restrict__ W,
    const float* __restrict__ bias, const int* __restrict__ perm,
    const float* __restrict__ gate, float* __restrict__ out) {
    __shared__ __align__(16) u16 As[2][128 * 64];   // 32 KB
    __shared__ __align__(16) u16 Bs[2][128 * 64];   // 32 KB
    __shared__ int   perm_s[128];
    __shared__ float gate_s[128];

    const int tid = threadIdx.x;
    const int bid = blockIdx.x;

    if (bid < 64) {                 // ---- zero rows of dropped tokens ----
        const int t = bid * 128 + (tid >> 2);
        if (gate[t] == 0.f) {
            const int part = tid & 3;
            float4 z = make_float4(0.f, 0.f, 0.f, 0.f);
            float4* o = (float4*)(out + (size_t)t * H + part * 256);
            #pragma unroll
            for (int i = 0; i < 64; ++i) o[i] = z;
        }
        return;
    }

    const int idx = bid - 64;
    const int fb = idx >> 6;          // feature block
    const int mb = (idx >> 3) & 7;    // slot block
    const int e  = idx & 7;           // expert -> XCD (W_e stays in one L2)

    if (tid < 128) {
        const int t = perm[e * CAP + mb * 128 + tid];
        perm_s[tid] = t;
        gate_s[tid] = (t >= 0) ? gate[t] : 0.f;
    }
    __syncthreads();

    const int lane = tid & 63;
    const int wv = tid >> 6;          // 0..7
    const int wm = wv >> 2;           // 0..1 : 64-row half
    const int wn = wv & 3;            // 0..3 : 32-col quarter
    const int l16 = lane & 15, quad = lane >> 4;

    // staging geometry: wave wv covers rows [wv*16, wv*16+16), 8 rows/q-step.
    // LDS[r][slot] = G[r][slot ^ (r&7)]; A achieves this by pre-swizzling the
    // global chunk (gch), B by writing lane-linear slot cch after loading gch.
    const int rl  = lane >> 3;        // row within 8-row group
    const int cch = lane & 7;
    const int gch = cch ^ rl;
    const u16*   ga[2];
    const float* gb[2];
    #pragma unroll
    for (int q = 0; q < 2; ++q) {
        const int r = wv * 16 + q * 8 + rl;
        const int tA = perm_s[r];
        const int tok = tA >= 0 ? tA : 0;
        ga[q] = xbf + (size_t)tok * H + gch * 8;
        gb[q] = W + (size_t)e * H * H + (size_t)(fb * 128 + r) * H + gch * 8;
    }

    f32x4 acc[4][2] = {};

    // prologue: load+convert B for kt=0
    uint4 pw[4];
    #pragma unroll
    for (int hb = 0; hb < 2; ++hb)
        #pragma unroll
        for (int q = 0; q < 2; ++q) {
            const float4* p = (const float4*)(gb[q] + hb * 64);
            const float4 v0 = p[0], v1 = p[1];
            uint4 v;
            v.x = cvt2bf(v0.x, v0.y); v.y = cvt2bf(v0.z, v0.w);
            v.z = cvt2bf(v1.x, v1.y); v.w = cvt2bf(v1.z, v1.w);
            pw[hb * 2 + q] = v;
        }

    for (int kt = 0; kt < H / 128; ++kt) {
        __syncthreads();
        #pragma unroll
        for (int hb = 0; hb < 2; ++hb)
            #pragma unroll
            for (int q = 0; q < 2; ++q) {
                u16* la = &As[hb][(wv * 16 + q * 8) * 64 + lane * 8];
                gld16(ga[q] + hb * 64, la);
            }
        #pragma unroll
        for (int hb = 0; hb < 2; ++hb)
            #pragma unroll
            for (int q = 0; q < 2; ++q)
                *(uint4*)&Bs[hb][(wv * 16 + q * 8 + rl) * 64 + cch * 8] = pw[hb * 2 + q];
        #pragma unroll
        for (int q = 0; q < 2; ++q) { ga[q] += 128; gb[q] += 128; }
        __syncthreads();

        if (kt < H / 128 - 1) {       // prefetch next-kt B during compute
            #pragma unroll
            for (int hb = 0; hb < 2; ++hb)
                #pragma unroll
                for (int q = 0; q < 2; ++q) {
                    const float4* p = (const float4*)(gb[q] + hb * 64);
                    const float4 v0 = p[0], v1 = p[1];
                    uint4 v;
                    v.x = cvt2bf(v0.x, v0.y); v.y = cvt2bf(v0.z, v0.w);
                    v.z = cvt2bf(v1.x, v1.y); v.w = cvt2bf(v1.z, v1.w);
                    pw[hb * 2 + q] = v;
                }
        }

        #pragma unroll
        for (int hb = 0; hb < 2; ++hb)
            #pragma unroll
            for (int s = 0; s < 2; ++s) {
                bf16x8 af[4], bfr[2];
                const int cc = (s * 4 + quad) ^ (l16 & 7);
                #pragma unroll
                for (int i = 0; i < 4; ++i)
                    af[i] = *(const bf16x8*)&As[hb][(wm * 64 + i * 16 + l16) * 64 + cc * 8];
                #pragma unroll
                for (int i = 0; i < 2; ++i)
                    bfr[i] = *(const bf16x8*)&Bs[hb][(wn * 32 + i * 16 + l16) * 64 + cc * 8];
                #pragma unroll
                for (int mi = 0; mi < 4; ++mi)
                    #pragma unroll
                    for (int ni = 0; ni < 2; ++ni)
                        acc[mi][ni] = __builtin_amdgcn_mfma_f32_16x16x32_bf16(
                            af[mi], bfr[ni], acc[mi][ni], 0, 0, 0);
            }
    }

    // epilogue: C/D layout col=lane&15, row=quad*4+reg
    float bv[2];
    #pragma unroll
    for (int ni = 0; ni < 2; ++ni)
        bv[ni] = bias[e * H + fb * 128 + wn * 32 + ni * 16 + l16];

    #pragma unroll
    for (int mi = 0; mi < 4; ++mi) {
        #pragma unroll
        for (int r = 0; r < 4; ++r) {
            const int rowl = wm * 64 + mi * 16 + quad * 4 + r;
            const int t = perm_s[rowl];
            if (t < 0) continue;
            const float g = gate_s[rowl];
            float* orow = out + (size_t)t * H + fb * 128 + wn * 32;
            #pragma unroll
            for (int ni = 0; ni < 2; ++ni)
                orow[ni * 16 + l16] = g * (acc[mi][ni][r] + bv[ni]);
        }
    }
}

extern "C" void kernel_launch(void* const* d_in, const int* in_sizes, int n_in,
                              void* d_out, int out_size, void* d_ws, size_t ws_size,
                              hipStream_t stream) {
    const float* x    = (const float*)d_in[0];  // [T,H]
    const float* wg   = (const float*)d_in[1];  // [H,E]
    const float* W    = (const float*)d_in[2];  // [E,H,H]
    const float* bias = (const float*)d_in[3];  // [E,H]
    float* out = (float*)d_out;

    // ws: eid[T] | gate[T] | perm[E*CAP] | xbf[T*H] bf16
    int*   eid  = (int*)d_ws;
    float* gate = (float*)((char*)d_ws + (size_t)T * 4);
    int*   perm = (int*)((char*)d_ws + (size_t)T * 8);
    u16*   xbf  = (u16*)((char*)d_ws + (size_t)T * 12);

    gate_kernel<<<T / 16, 256, 0, stream>>>(x, wg, eid, gate, xbf);
    scan_kernel<<<1, SCAN_T, 0, stream>>>(eid, gate, perm);
    moe_gemm_bf<<<64 + 512, 512, 0, stream>>>(xbf, W, bias, perm, gate, out);
}